// Round 1
// baseline (213.076 us; speedup 1.0000x reference)
//
#include <hip/hip_runtime.h>

// TrigHashGrid: B=1048576, IN_DIM=3, M=3, N=16, C=2, W=1000, A=-0.75
// Thread = (b, n). Block: 512 threads = 64 b's x 8 n's; blockIdx parity picks
// which half of the 16 levels (so LDS grids stage = 64 KB -> 2 blocks/CU).
// grids staged in LDS transposed to (n, w, c) so one ds_read_b64 fetches both
// channels of a tap. Output written as float2 (coalesced 64B segments).

constexpr int B_TOT = 1048576;
constexpr float A_C = -0.75f;

__device__ __forceinline__ float cubic_inner(float s) {
    return ((A_C + 2.0f) * s - (A_C + 3.0f)) * s * s + 1.0f;
}
__device__ __forceinline__ float cubic_outer(float s) {
    return ((A_C * s - 5.0f * A_C) * s + 8.0f * A_C) * s - 4.0f * A_C;
}

// |x| <= ~200 here (a ~ N(0,17) tails + H). Cody-Waite 2-term pi/2 reduction
// + cephes minimax polys: abs err ~1.5e-7, no libm slow-path VGPR bloat.
__device__ __forceinline__ float fast_sin(float x) {
    float kf = rintf(x * 0.63661977236758134f);            // x * 2/pi
    float r  = fmaf(-kf, 1.57079637f, x);                  // f32(pi/2), exact fma
    r        = fmaf(kf, 4.37113900e-8f, r);                // f32(pi/2) - pi/2
    int q = (int)kf;
    float r2 = r * r;
    float sp = fmaf(r2, fmaf(r2, -1.9515295891e-4f, 8.3321608736e-3f),
                    -1.6666654611e-1f);
    sp = fmaf(r * r2, sp, r);                              // sin(r)
    float cp = fmaf(r2, fmaf(r2, 2.4433157118e-5f, -1.3887316255e-3f),
                    4.1666645683e-2f);
    float c  = fmaf(r2 * r2, cp, fmaf(r2, -0.5f, 1.0f));   // cos(r)
    float res = (q & 1) ? c : sp;
    return (q & 2) ? -res : res;
}

#define BLK 512

__global__ __launch_bounds__(BLK, 4)
void trig_hashgrid(const float* __restrict__ x, const float* __restrict__ grids,
                   const float* __restrict__ G, const float* __restrict__ H,
                   float* __restrict__ out)
{
    __shared__ float lds[16000];              // 8 levels x 1000 w x 2 c = 64 KB
    const int tid  = threadIdx.x;
    const int half = blockIdx.x & 1;          // which 8 of the 16 levels
    const int blk  = blockIdx.x >> 1;         // 0..1023

    // Stage grids[half*8 .. half*8+8) : global (n,c,w) -> LDS (n_loc, w, c).
    // Global reads fully coalesced (grids[half*16000 + i]).
    for (int i = tid; i < 16000; i += BLK) {
        int n_loc = i / 2000;
        int rem   = i - n_loc * 2000;
        int c     = rem / 1000;
        int w     = rem - c * 1000;
        lds[n_loc * 2000 + w * 2 + c] = grids[half * 16000 + i];
    }

    const int n_loc = tid & 7;
    const int n     = half * 8 + n_loc;       // fixed per thread
    const int g     = tid >> 3;               // 0..63

    // Preload per-level frequencies/phases into registers (reused 16 iters).
    float G0[3], G1[3], G2[3], Hr[3];
#pragma unroll
    for (int m = 0; m < 3; ++m) {
        G0[m] = G[0 * 48 + m * 16 + n];
        G1[m] = G[1 * 48 + m * 16 + n];
        G2[m] = G[2 * 48 + m * 16 + n];
        Hr[m] = H[m * 16 + n];
    }
    __syncthreads();

    float2* __restrict__ out2 = (float2*)out;
    const float* lrow = &lds[n_loc * 2000];

    // b covers [0, 65536) per sweep, stride 65536 -> 16 iterations.
    for (int b = blk * 64 + g; b < B_TOT; b += 1024 * 64) {
        float x0 = x[b * 3 + 0];
        float x1 = x[b * 3 + 1];
        float x2 = x[b * 3 + 2];

        float p = 1.0f;
#pragma unroll
        for (int m = 0; m < 3; ++m) {
            float a = fmaf(x2, G2[m], fmaf(x1, G1[m], x0 * G0[m])) + Hr[m];
            p *= fast_sin(a);
        }

        float ix = ((p + 1.0f) * 1000.0f - 1.0f) * 0.5f;   // [-0.5, 999.5]
        float xf = floorf(ix);
        float t  = ix - xf;
        int base = (int)xf;

        float wt[4];
        wt[0] = cubic_outer(t + 1.0f);
        wt[1] = cubic_inner(t);
        wt[2] = cubic_inner(1.0f - t);
        wt[3] = cubic_outer(2.0f - t);

        float o0 = 0.0f, o1 = 0.0f;
#pragma unroll
        for (int k = 0; k < 4; ++k) {
            int idx  = base + k - 1;
            float wv = (idx >= 0 && idx < 1000) ? wt[k] : 0.0f;
            int idxc = min(max(idx, 0), 999);
            float2 v = *(const float2*)(lrow + idxc * 2);  // ds_read_b64
            o0 = fmaf(v.x, wv, o0);
            o1 = fmaf(v.y, wv, o1);
        }
        // out[b, n, c] flat = b*32 + n*2 + c  -> float2 at b*16 + n
        out2[b * 16 + n] = make_float2(o0, o1);
    }
}

extern "C" void kernel_launch(void* const* d_in, const int* in_sizes, int n_in,
                              void* d_out, int out_size, void* d_ws, size_t ws_size,
                              hipStream_t stream) {
    const float* x     = (const float*)d_in[0];
    const float* grids = (const float*)d_in[1];
    const float* G     = (const float*)d_in[2];
    const float* H     = (const float*)d_in[3];
    float* out = (float*)d_out;
    trig_hashgrid<<<2048, BLK, 0, stream>>>(x, grids, G, H, out);
}